// Round 4
// baseline (722.821 us; speedup 1.0000x reference)
//
#include <hip/hip_runtime.h>
#include <stdint.h>

#define NN 50000
#define CC 1024
#define HH 128
#define EE 1600000
#define EPSV 1e-8f
#define SCAN_BLKS 196   // ceil(50000/256)

typedef __attribute__((ext_vector_type(8))) short bf16x8;
typedef __attribute__((ext_vector_type(4))) float f32x4;
typedef __attribute__((ext_vector_type(2))) float f32x2;

__device__ __forceinline__ unsigned short f32_to_bf16(float f){
  union { float f; uint32_t u; } cv; cv.f = f;
  uint32_t u = cv.u;
  return (unsigned short)((u + 0x7FFFu + ((u >> 16) & 1u)) >> 16);
}
__device__ __forceinline__ float bf16lo_to_f32(uint32_t w){
  union { uint32_t u; float f; } cv; cv.u = w << 16; return cv.f;
}
__device__ __forceinline__ float bf16hi_to_f32(uint32_t w){
  union { uint32_t u; float f; } cv; cv.u = w & 0xFFFF0000u; return cv.f;
}

// ---------------- prep kernels ----------------

__global__ __launch_bounds__(256) void k_prep_w1t(const float* __restrict__ W1,
                                                  unsigned short* __restrict__ W1T){
  int idx = blockIdx.x*256 + threadIdx.x;          // 128*1024, W1T[n][k]
  if(idx >= 128*1024) return;
  int n = idx >> 10, k = idx & 1023;
  W1T[idx] = f32_to_bf16(W1[k*128 + n]);
}

__global__ __launch_bounds__(256) void k_prep_w2t(const float* __restrict__ W2,
                                                  unsigned short* __restrict__ W2T){
  int idx = blockIdx.x*256 + threadIdx.x;          // 128*128, W2T[n][k]
  if(idx >= 128*128) return;
  int n = idx >> 7, k = idx & 127;
  W2T[idx] = f32_to_bf16(W2[k*128 + n]);
}

// Wg1T[c][k], c in [0,256): c<128 -> u-col uses Wg1[k][c]; c>=128 -> v-col uses Wg1[128+k][c-128]
__global__ __launch_bounds__(256) void k_prep_wg1T(const float* __restrict__ Wg1,
                                                   unsigned short* __restrict__ T){
  int idx = blockIdx.x*256 + threadIdx.x;          // 256*128
  if(idx >= 256*128) return;
  int c = idx >> 7, k = idx & 127;
  int row = (c < 128) ? k : (128 + k);
  int col = (c < 128) ? c : (c - 128);
  T[idx] = f32_to_bf16(Wg1[row*128 + col]);
}

// ---------------- CSR build: hist + 3-kernel parallel scan + fill ----------------

__global__ __launch_bounds__(256) void k_hist(const int* __restrict__ dst,
                                              int* __restrict__ counts){
  int e = blockIdx.x*256 + threadIdx.x;
  if(e < EE) atomicAdd(&counts[dst[e]], 1);
}

__global__ __launch_bounds__(256) void k_scan1(const int* __restrict__ counts,
    int* __restrict__ lexcl, int* __restrict__ bsum){
  __shared__ int buf[256];
  const int t = threadIdx.x, i = blockIdx.x*256 + t;
  int v = (i < NN) ? counts[i] : 0;
  buf[t] = v;
  __syncthreads();
  for(int off = 1; off < 256; off <<= 1){
    int add = (t >= off) ? buf[t-off] : 0;
    __syncthreads();
    buf[t] += add;
    __syncthreads();
  }
  if(i < NN) lexcl[i] = buf[t] - v;
  if(t == 255) bsum[blockIdx.x] = buf[255];
}

__global__ __launch_bounds__(256) void k_scan2(const int* __restrict__ bsum,
    int* __restrict__ bexcl, int* __restrict__ row_ptr){
  __shared__ int buf[256];
  const int t = threadIdx.x;
  int v = (t < SCAN_BLKS) ? bsum[t] : 0;
  buf[t] = v;
  __syncthreads();
  for(int off = 1; off < 256; off <<= 1){
    int add = (t >= off) ? buf[t-off] : 0;
    __syncthreads();
    buf[t] += add;
    __syncthreads();
  }
  if(t < SCAN_BLKS) bexcl[t] = buf[t] - v;
  if(t == 255) row_ptr[NN] = buf[255];
}

__global__ __launch_bounds__(256) void k_scan3(const int* __restrict__ lexcl,
    const int* __restrict__ bexcl, int* __restrict__ row_ptr, int* __restrict__ cursor){
  const int i = blockIdx.x*256 + threadIdx.x;
  if(i >= NN) return;
  int e = lexcl[i] + bexcl[blockIdx.x];
  row_ptr[i] = e;
  cursor[i]  = e;
}

// fill CSR slots; computes c = base_w*sig(rho_src)*sig(rho_dst) inline into permuted order
__global__ __launch_bounds__(256) void k_fill(const int* __restrict__ src,
    const int* __restrict__ dst, const float* __restrict__ base_w,
    const float* __restrict__ rho_raw, int* __restrict__ cursor,
    int* __restrict__ src_perm, float* __restrict__ c_perm){
  int e = blockIdx.x*256 + threadIdx.x;
  if(e >= EE) return;
  int s = src[e], d = dst[e];
  int p = atomicAdd(&cursor[d], 1);
  float rs = 1.f/(1.f + __expf(-rho_raw[s]));
  float rd = 1.f/(1.f + __expf(-rho_raw[d]));
  src_perm[p] = s;
  c_perm[p]   = base_w[e]*rs*rd;
}

// ---------------- encoder GEMM1: h1 = relu(X@W1 + b1) -> bf16 [N,128] ----------------
// No LDS, no barriers. 4 waves/block, each wave owns a 16x128 output tile.
// A-frags streamed from global X (coalesced 128B/row per K-step), B-frags from
// L2-resident W1T, one-iteration A-prefetch, compiler-scheduled vmcnt pipeline.

__global__ __launch_bounds__(256) void k_enc1(
    const float* __restrict__ X, const unsigned short* __restrict__ W1T,
    const float* __restrict__ b1, unsigned short* __restrict__ h1)
{
  const int t = threadIdx.x, wave = t >> 6, lane = t & 63;
  const int rowL = lane & 15, kq = lane >> 4;
  const int row0 = blockIdx.x*64 + wave*16;

  int ar = row0 + rowL; if(ar >= NN) ar = NN-1;     // A row this lane streams
  const float* xp = X + (size_t)ar*1024 + kq*8;
  const unsigned short* wp = W1T + (size_t)rowL*1024 + kq*8;

  f32x4 acc[8] = {};
  f32x4 c0 = *(const f32x4*)(xp);
  f32x4 c1 = *(const f32x4*)(xp + 4);

  #pragma unroll 2
  for(int k0 = 0; k0 < 1024; k0 += 32){
    const int kn = (k0 + 32) & 1023;                 // wraps to 0 on last iter (harmless)
    f32x4 n0 = *(const f32x4*)(xp + kn);
    f32x4 n1 = *(const f32x4*)(xp + kn + 4);
    union { bf16x8 v; unsigned short s[8]; } pk;
    #pragma unroll
    for(int j = 0; j < 4; j++){ pk.s[j] = f32_to_bf16(c0[j]); pk.s[4+j] = f32_to_bf16(c1[j]); }
    #pragma unroll
    for(int nt = 0; nt < 8; nt++){
      bf16x8 b = *(const bf16x8*)(wp + nt*16384 + k0);
      acc[nt] = __builtin_amdgcn_mfma_f32_16x16x32_bf16(pk.v, b, acc[nt], 0, 0, 0);
    }
    c0 = n0; c1 = n1;
  }

  // C layout: row = row0 + kq*4 + r, col = nt*16 + rowL
  #pragma unroll
  for(int nt = 0; nt < 8; nt++){
    const int col = nt*16 + rowL;
    const float bv = b1[col];
    #pragma unroll
    for(int r = 0; r < 4; r++){
      const int gr = row0 + kq*4 + r;
      if(gr < NN) h1[(size_t)gr*128 + col] = f32_to_bf16(fmaxf(acc[nt][r] + bv, 0.f));
    }
  }
}

// ---------------- shared UV phase: [u|v] = h @ Wg1T from swizzled LDS h ----------------
// hs: 64 rows x 128 bf16, chunk c of row r stored at chunk (c ^ (r&15)).

__device__ __forceinline__ void uv_phase2(
    const unsigned short* hs, int row0, int wave, int lane,
    const unsigned short* __restrict__ Wg1T, const float* __restrict__ bg1,
    unsigned short* __restrict__ UH, float* __restrict__ Vf)
{
  const int rowL = lane & 15, kq = lane >> 4;
  const int r = wave*16 + rowL;                      // A row (local)
  f32x4 acc[16] = {};
  #pragma unroll
  for(int ks = 0; ks < 4; ks++){
    const int kc = ks*4 + kq;
    bf16x8 a = *(const bf16x8*)&hs[r*128 + ((kc ^ (r & 15)) << 3)];
    #pragma unroll
    for(int nt = 0; nt < 16; nt++){
      bf16x8 b = *(const bf16x8*)(Wg1T + (size_t)(nt*16 + rowL)*128 + ks*32 + kq*8);
      acc[nt] = __builtin_amdgcn_mfma_f32_16x16x32_bf16(a, b, acc[nt], 0, 0, 0);
    }
  }
  #pragma unroll
  for(int nt = 0; nt < 16; nt++){
    const int col = nt*16 + rowL;
    #pragma unroll
    for(int rr = 0; rr < 4; rr++){
      const int gr = row0 + wave*16 + kq*4 + rr;
      if(gr < NN){
        if(col < 128) UH[(size_t)gr*256 + col] = f32_to_bf16(acc[nt][rr]);
        else          Vf[(size_t)gr*128 + col - 128] = acc[nt][rr] + bg1[col - 128];
      }
    }
  }
}

// ---------------- k_uvA: h = relu(h1@W2T + b2); writes UH=[u|h] bf16, Vf=v+bg1 ----------------

__global__ __launch_bounds__(256) void k_uvA(
    const unsigned short* __restrict__ h1, const unsigned short* __restrict__ W2T,
    const float* __restrict__ b2, const unsigned short* __restrict__ Wg1T,
    const float* __restrict__ bg1, unsigned short* __restrict__ UH,
    float* __restrict__ Vf)
{
  __shared__ __attribute__((aligned(16))) unsigned short hs[64*128];
  const int t = threadIdx.x, wave = t >> 6, lane = t & 63;
  const int rowL = lane & 15, kq = lane >> 4;
  const int row0 = blockIdx.x*64;

  // phase 1: h = relu(h1 @ W2T + b2); A direct from global h1, B from L2-resident W2T
  int ar = row0 + wave*16 + rowL; if(ar >= NN) ar = NN-1;
  f32x4 acc[8] = {};
  #pragma unroll
  for(int ks = 0; ks < 4; ks++){
    bf16x8 a = *(const bf16x8*)(h1 + (size_t)ar*128 + ks*32 + kq*8);
    #pragma unroll
    for(int nt = 0; nt < 8; nt++){
      bf16x8 b = *(const bf16x8*)(W2T + (nt*16 + rowL)*128 + ks*32 + kq*8);
      acc[nt] = __builtin_amdgcn_mfma_f32_16x16x32_bf16(a, b, acc[nt], 0, 0, 0);
    }
  }
  // h -> swizzled LDS (bf16 scalars)
  #pragma unroll
  for(int nt = 0; nt < 8; nt++){
    const int col = nt*16 + rowL;
    const float bv = b2[col];
    #pragma unroll
    for(int r = 0; r < 4; r++){
      const int rw = wave*16 + kq*4 + r;
      const unsigned short hv = f32_to_bf16(fmaxf(acc[nt][r] + bv, 0.f));
      hs[rw*128 + (((col >> 3) ^ (rw & 15)) << 3) + (col & 7)] = hv;
    }
  }
  __syncthreads();
  // copy h to UH h-half (coalesced 16B)
  {
    const int r = t >> 2, gr = row0 + r;
    if(gr < NN){
      #pragma unroll
      for(int j8 = 0; j8 < 4; j8++){
        const int chunk = (t & 3)*4 + j8;
        bf16x8 v = *(const bf16x8*)&hs[r*128 + ((chunk ^ (r & 15)) << 3)];
        *(bf16x8*)&UH[(size_t)gr*256 + 128 + chunk*8] = v;
      }
    }
  }
  uv_phase2(hs, row0, wave, lane, Wg1T, bg1, UH, Vf);
}

// ---------------- k_uvB: input h f32 (agg output); writes UH=[u|h] bf16, Vf=v+bg1 ----------------

__global__ __launch_bounds__(256) void k_uvB(
    const float* __restrict__ hf, const unsigned short* __restrict__ Wg1T,
    const float* __restrict__ bg1, unsigned short* __restrict__ UH,
    float* __restrict__ Vf)
{
  __shared__ __attribute__((aligned(16))) unsigned short hs[64*128];
  const int t = threadIdx.x, wave = t >> 6, lane = t & 63;
  const int row0 = blockIdx.x*64;

  {
    const int r = t >> 2, gr0 = row0 + r;
    const int gr = (gr0 < NN) ? gr0 : NN-1;
    const float* p = hf + (size_t)gr*128 + (t & 3)*32;
    #pragma unroll
    for(int j8 = 0; j8 < 4; j8++){
      f32x4 v0 = *(const f32x4*)(p + j8*8);
      f32x4 v1 = *(const f32x4*)(p + j8*8 + 4);
      union { bf16x8 v; unsigned short s[8]; } pk;
      #pragma unroll
      for(int j = 0; j < 4; j++){ pk.s[j] = f32_to_bf16(v0[j]); pk.s[4+j] = f32_to_bf16(v1[j]); }
      const int chunk = (t & 3)*4 + j8;
      *(bf16x8*)&hs[r*128 + ((chunk ^ (r & 15)) << 3)] = pk.v;
      if(gr0 < NN) *(bf16x8*)&UH[(size_t)gr0*256 + 128 + chunk*8] = pk.v;
    }
  }
  __syncthreads();
  uv_phase2(hs, row0, wave, lane & 63, Wg1T, bg1, UH, Vf);
}

// ---------------- fused gate + aggregation, CSR order, one wave per dst node ----------------

__global__ __launch_bounds__(256) void k_gate_agg(
    const unsigned short* __restrict__ UH, const float* __restrict__ Vf,
    const int* __restrict__ row_ptr, const int* __restrict__ src_perm,
    const float* __restrict__ c_perm,
    const float* __restrict__ Wg2, const float* __restrict__ bg2p,
    float* __restrict__ out_f32)
{
  __shared__ float2 ws_s[4][64];
  const int wv = threadIdx.x >> 6, lane = threadIdx.x & 63;
  const int gw = blockIdx.x*4 + wv;
  if(gw >= NN) return;
  const int eq = lane >> 4, li = lane & 15;

  f32x4 va = *(const f32x4*)(Vf + (size_t)gw*128 + li*8);
  f32x4 vb = *(const f32x4*)(Vf + (size_t)gw*128 + li*8 + 4);
  f32x4 wa = *(const f32x4*)(Wg2 + li*8);
  f32x4 wb = *(const f32x4*)(Wg2 + li*8 + 4);
  const float vch[8]  = {va[0],va[1],va[2],va[3],vb[0],vb[1],vb[2],vb[3]};
  const float w2ch[8] = {wa[0],wa[1],wa[2],wa[3],wb[0],wb[1],wb[2],wb[3]};
  const float bg2v = bg2p[0];

  const int beg = row_ptr[gw], end = row_ptr[gw+1];
  float a0 = 0.f, a1 = 0.f, wsum = 0.f;

  for(int base = beg; base < end; base += 64){
    const int nb = min(64, end - base);
    for(int q = 0; q < nb; q += 4){
      const int  idx  = q + eq;
      const bool ok   = (idx < nb);
      const int  slot = base + (ok ? idx : 0);
      const int  s    = src_perm[slot];
      const float cv  = c_perm[slot];
      union { bf16x8 v; uint32_t u32[4]; } uu;
      uu.v = *(const bf16x8*)&UH[(size_t)s*256 + li*8];
      float tacc = 0.f;
      #pragma unroll
      for(int p = 0; p < 4; p++){
        const uint32_t w2b = uu.u32[p];
        tacc += fmaxf(bf16lo_to_f32(w2b) + vch[2*p],   0.f) * w2ch[2*p];
        tacc += fmaxf(bf16hi_to_f32(w2b) + vch[2*p+1], 0.f) * w2ch[2*p+1];
      }
      tacc += __int_as_float(__builtin_amdgcn_ds_swizzle(__float_as_int(tacc), 0x041F));
      tacc += __int_as_float(__builtin_amdgcn_ds_swizzle(__float_as_int(tacc), 0x081F));
      tacc += __int_as_float(__builtin_amdgcn_ds_swizzle(__float_as_int(tacc), 0x101F));
      tacc += __int_as_float(__builtin_amdgcn_ds_swizzle(__float_as_int(tacc), 0x201F));
      const float g = 1.f/(1.f + __expf(-(tacc + bg2v)));
      if(li == 0 && ok) ws_s[wv][idx] = make_float2(cv*g, __int_as_float(s));
    }
    #pragma unroll 4
    for(int j = 0; j < nb; j++){
      const float2 p = ws_s[wv][j];
      const float w  = p.x;
      const int   s  = __float_as_int(p.y);
      const uint32_t hw = *(const uint32_t*)&UH[(size_t)s*256 + 128 + lane*2];
      a0 += w*bf16lo_to_f32(hw);
      a1 += w*bf16hi_to_f32(hw);
      wsum += w;
    }
  }
  const float inv = 1.f/(wsum + EPSV);
  const size_t o = (size_t)gw*128 + lane*2;
  *(f32x2*)&out_f32[o] = (f32x2){a0*inv, a1*inv};
}

// ---------------- launch ----------------

extern "C" void kernel_launch(void* const* d_in, const int* in_sizes, int n_in,
                              void* d_out, int out_size, void* d_ws, size_t ws_size,
                              hipStream_t stream) {
  (void)in_sizes; (void)n_in; (void)out_size; (void)ws_size;
  const float* X      = (const float*)d_in[0];
  const int*   src    = (const int*)d_in[1];
  const int*   dst    = (const int*)d_in[2];
  const float* base_w = (const float*)d_in[3];
  const float* W1     = (const float*)d_in[4];
  const float* b1     = (const float*)d_in[5];
  const float* W2     = (const float*)d_in[6];
  const float* b2     = (const float*)d_in[7];
  const float* Wg1    = (const float*)d_in[8];
  const float* bg1    = (const float*)d_in[9];
  const float* Wg2    = (const float*)d_in[10];
  const float* bg2    = (const float*)d_in[11];
  const float* rho    = (const float*)d_in[12];

  char* ws = (char*)d_ws;
  size_t off = 0;
  auto alloc = [&](size_t bytes)->char*{ char* p = ws + off; off += (bytes + 255) & ~(size_t)255; return p; };
  unsigned short* W1T      = (unsigned short*)alloc((size_t)1024*128*2);
  unsigned short* W2T      = (unsigned short*)alloc((size_t)128*128*2);
  unsigned short* Wg1T     = (unsigned short*)alloc((size_t)256*128*2);
  int*            src_perm = (int*)alloc((size_t)EE*4);
  float*          c_perm   = (float*)alloc((size_t)EE*4);
  int*            row_ptr  = (int*)alloc((size_t)(NN+1)*4);
  int*            cursor   = (int*)alloc((size_t)NN*4);
  int*            counts   = (int*)alloc((size_t)NN*4);
  int*            lexcl    = (int*)alloc((size_t)NN*4);
  int*            bsum     = (int*)alloc((size_t)256*4);
  int*            bexcl    = (int*)alloc((size_t)256*4);
  unsigned short* h1       = (unsigned short*)alloc((size_t)NN*128*2);
  unsigned short* UH       = (unsigned short*)alloc((size_t)NN*256*2);
  float*          Vf       = (float*)alloc((size_t)NN*128*4);
  float*          hf_B     = (float*)alloc((size_t)NN*128*4);

  hipMemsetAsync(counts, 0, (size_t)NN*4, stream);
  k_prep_w1t<<<512, 256, 0, stream>>>(W1, W1T);
  k_prep_w2t<<<64, 256, 0, stream>>>(W2, W2T);
  k_prep_wg1T<<<128, 256, 0, stream>>>(Wg1, Wg1T);
  k_hist<<<EE/256, 256, 0, stream>>>(dst, counts);
  k_scan1<<<SCAN_BLKS, 256, 0, stream>>>(counts, lexcl, bsum);
  k_scan2<<<1, 256, 0, stream>>>(bsum, bexcl, row_ptr);
  k_scan3<<<SCAN_BLKS, 256, 0, stream>>>(lexcl, bexcl, row_ptr, cursor);
  k_fill<<<EE/256, 256, 0, stream>>>(src, dst, base_w, rho, cursor, src_perm, c_perm);

  k_enc1<<<782, 256, 0, stream>>>(X, W1T, b1, h1);

  // layer 1
  k_uvA<<<782, 256, 0, stream>>>(h1, W2T, b2, Wg1T, bg1, UH, Vf);
  k_gate_agg<<<12500, 256, 0, stream>>>(UH, Vf, row_ptr, src_perm, c_perm, Wg2, bg2, hf_B);
  // layer 2
  k_uvB<<<782, 256, 0, stream>>>(hf_B, Wg1T, bg1, UH, Vf);
  k_gate_agg<<<12500, 256, 0, stream>>>(UH, Vf, row_ptr, src_perm, c_perm, Wg2, bg2, (float*)d_out);
}

// Round 5
// 714.783 us; speedup vs baseline: 1.0112x; 1.0112x over previous
//
#include <hip/hip_runtime.h>
#include <stdint.h>

#define NN 50000
#define CC 1024
#define HH 128
#define EE 1600000
#define EPSV 1e-8f
#define SCAN_BLKS 196   // ceil(50000/256)

typedef __attribute__((ext_vector_type(8))) short bf16x8;
typedef __attribute__((ext_vector_type(4))) float f32x4;
typedef __attribute__((ext_vector_type(2))) float f32x2;

__device__ __forceinline__ unsigned short f32_to_bf16(float f){
  union { float f; uint32_t u; } cv; cv.f = f;
  uint32_t u = cv.u;
  return (unsigned short)((u + 0x7FFFu + ((u >> 16) & 1u)) >> 16);
}
__device__ __forceinline__ float bf16lo_to_f32(uint32_t w){
  union { uint32_t u; float f; } cv; cv.u = w << 16; return cv.f;
}
__device__ __forceinline__ float bf16hi_to_f32(uint32_t w){
  union { uint32_t u; float f; } cv; cv.u = w & 0xFFFF0000u; return cv.f;
}

// ---------------- prep kernels ----------------

__global__ __launch_bounds__(256) void k_prep_w1t(const float* __restrict__ W1,
                                                  unsigned short* __restrict__ W1T){
  int idx = blockIdx.x*256 + threadIdx.x;          // 128*1024, W1T[n][k]
  if(idx >= 128*1024) return;
  int n = idx >> 10, k = idx & 1023;
  W1T[idx] = f32_to_bf16(W1[k*128 + n]);
}

__global__ __launch_bounds__(256) void k_prep_w2t(const float* __restrict__ W2,
                                                  unsigned short* __restrict__ W2T){
  int idx = blockIdx.x*256 + threadIdx.x;          // 128*128, W2T[n][k]
  if(idx >= 128*128) return;
  int n = idx >> 7, k = idx & 127;
  W2T[idx] = f32_to_bf16(W2[k*128 + n]);
}

// Wg1T[c][k], c in [0,256): c<128 -> u-col uses Wg1[k][c]; c>=128 -> v-col uses Wg1[128+k][c-128]
__global__ __launch_bounds__(256) void k_prep_wg1T(const float* __restrict__ Wg1,
                                                   unsigned short* __restrict__ T){
  int idx = blockIdx.x*256 + threadIdx.x;          // 256*128
  if(idx >= 256*128) return;
  int c = idx >> 7, k = idx & 127;
  int row = (c < 128) ? k : (128 + k);
  int col = (c < 128) ? c : (c - 128);
  T[idx] = f32_to_bf16(Wg1[row*128 + col]);
}

// ---------------- CSR build: hist + 3-kernel parallel scan + fill ----------------

__global__ __launch_bounds__(256) void k_hist(const int* __restrict__ dst,
                                              int* __restrict__ counts){
  int e = blockIdx.x*256 + threadIdx.x;
  if(e < EE) atomicAdd(&counts[dst[e]], 1);
}

__global__ __launch_bounds__(256) void k_scan1(const int* __restrict__ counts,
    int* __restrict__ lexcl, int* __restrict__ bsum){
  __shared__ int buf[256];
  const int t = threadIdx.x, i = blockIdx.x*256 + t;
  int v = (i < NN) ? counts[i] : 0;
  buf[t] = v;
  __syncthreads();
  for(int off = 1; off < 256; off <<= 1){
    int add = (t >= off) ? buf[t-off] : 0;
    __syncthreads();
    buf[t] += add;
    __syncthreads();
  }
  if(i < NN) lexcl[i] = buf[t] - v;
  if(t == 255) bsum[blockIdx.x] = buf[255];
}

__global__ __launch_bounds__(256) void k_scan2(const int* __restrict__ bsum,
    int* __restrict__ bexcl, int* __restrict__ row_ptr){
  __shared__ int buf[256];
  const int t = threadIdx.x;
  int v = (t < SCAN_BLKS) ? bsum[t] : 0;
  buf[t] = v;
  __syncthreads();
  for(int off = 1; off < 256; off <<= 1){
    int add = (t >= off) ? buf[t-off] : 0;
    __syncthreads();
    buf[t] += add;
    __syncthreads();
  }
  if(t < SCAN_BLKS) bexcl[t] = buf[t] - v;
  if(t == 255) row_ptr[NN] = buf[255];
}

__global__ __launch_bounds__(256) void k_scan3(const int* __restrict__ lexcl,
    const int* __restrict__ bexcl, int* __restrict__ row_ptr, int* __restrict__ cursor){
  const int i = blockIdx.x*256 + threadIdx.x;
  if(i >= NN) return;
  int e = lexcl[i] + bexcl[blockIdx.x];
  row_ptr[i] = e;
  cursor[i]  = e;
}

// fill CSR slots; computes c = base_w*sig(rho_src)*sig(rho_dst) inline into permuted order
__global__ __launch_bounds__(256) void k_fill(const int* __restrict__ src,
    const int* __restrict__ dst, const float* __restrict__ base_w,
    const float* __restrict__ rho_raw, int* __restrict__ cursor,
    int* __restrict__ src_perm, float* __restrict__ c_perm){
  int e = blockIdx.x*256 + threadIdx.x;
  if(e >= EE) return;
  int s = src[e], d = dst[e];
  int p = atomicAdd(&cursor[d], 1);
  float rs = 1.f/(1.f + __expf(-rho_raw[s]));
  float rd = 1.f/(1.f + __expf(-rho_raw[d]));
  src_perm[p] = s;
  c_perm[p]   = base_w[e]*rs*rd;
}

// ---------------- encoder GEMM1: h1 = relu(X@W1 + b1) -> bf16 [N,128] ----------------
// Split-K x4: 512-thread blocks, wave (m,q) = 16-row M-subtile x 256-col K-quarter.
// 12504 waves total (4x TLP vs round 4), depth-2 A prefetch, LDS tree-reduce (33KB).

__global__ __launch_bounds__(512) void k_enc1(
    const float* __restrict__ X, const unsigned short* __restrict__ W1T,
    const float* __restrict__ b1, unsigned short* __restrict__ h1)
{
  __shared__ __attribute__((aligned(16))) float red[2][2][16][132];
  const int t = threadIdx.x, w = t >> 6, lane = t & 63;
  const int m = w & 1, q = w >> 1;                 // M-subtile, K-quarter
  const int rowL = lane & 15, kq = lane >> 4;
  const int row0 = blockIdx.x*32 + m*16;

  int ar = row0 + rowL; if(ar >= NN) ar = NN-1;
  const float* xp = X + (size_t)ar*1024 + q*256 + kq*8;
  const unsigned short* wp = W1T + (size_t)rowL*1024 + q*256 + kq*8;

  f32x4 acc[8] = {};
  f32x4 paA0 = *(const f32x4*)(xp),      paA1 = *(const f32x4*)(xp + 4);
  f32x4 paB0 = *(const f32x4*)(xp + 32), paB1 = *(const f32x4*)(xp + 36);

  #pragma unroll
  for(int i = 0; i < 8; i++){
    f32x4 c0, c1;
    if(i & 1){ c0 = paB0; c1 = paB1; } else { c0 = paA0; c1 = paA1; }
    // prefetch iteration i+2
    f32x4 n0, n1;
    if(i < 6){
      n0 = *(const f32x4*)(xp + (i+2)*32);
      n1 = *(const f32x4*)(xp + (i+2)*32 + 4);
    }
    union { bf16x8 v; unsigned short s[8]; } pk;
    #pragma unroll
    for(int j = 0; j < 4; j++){ pk.s[j] = f32_to_bf16(c0[j]); pk.s[4+j] = f32_to_bf16(c1[j]); }
    #pragma unroll
    for(int nt = 0; nt < 8; nt++){
      bf16x8 b = *(const bf16x8*)(wp + nt*16384 + i*32);
      acc[nt] = __builtin_amdgcn_mfma_f32_16x16x32_bf16(pk.v, b, acc[nt], 0, 0, 0);
    }
    if(i < 6){
      if(i & 1){ paB0 = n0; paB1 = n1; } else { paA0 = n0; paA1 = n1; }
    }
  }

  // LDS tree reduction over q: (q2,q3) -> (q0,q1), then q1 -> q0.
  if(q >= 2){
    float* rg = &red[q-2][m][0][0];
    #pragma unroll
    for(int nt = 0; nt < 8; nt++)
      #pragma unroll
      for(int r = 0; r < 4; r++)
        rg[(kq*4+r)*132 + nt*16 + rowL] = acc[nt][r];
  }
  __syncthreads();
  if(q < 2){
    const float* rg = &red[q][m][0][0];
    #pragma unroll
    for(int nt = 0; nt < 8; nt++)
      #pragma unroll
      for(int r = 0; r < 4; r++)
        acc[nt][r] += rg[(kq*4+r)*132 + nt*16 + rowL];
  }
  __syncthreads();
  if(q == 1){
    float* rg = &red[0][m][0][0];
    #pragma unroll
    for(int nt = 0; nt < 8; nt++)
      #pragma unroll
      for(int r = 0; r < 4; r++)
        rg[(kq*4+r)*132 + nt*16 + rowL] = acc[nt][r];
  }
  __syncthreads();
  if(q == 0){
    const float* rg = &red[0][m][0][0];
    #pragma unroll
    for(int nt = 0; nt < 8; nt++){
      const int col = nt*16 + rowL;
      const float bv = b1[col];
      #pragma unroll
      for(int r = 0; r < 4; r++){
        const float v = acc[nt][r] + rg[(kq*4+r)*132 + col] + bv;
        const int gr = row0 + kq*4 + r;
        if(gr < NN) h1[(size_t)gr*128 + col] = f32_to_bf16(fmaxf(v, 0.f));
      }
    }
  }
}

// ---------------- shared UV phase: [u|v] = h @ Wg1T from swizzled LDS h ----------------
// hs: 64 rows x 128 bf16, chunk c of row r stored at chunk (c ^ (r&15)).

__device__ __forceinline__ void uv_phase2(
    const unsigned short* hs, int row0, int wave, int lane,
    const unsigned short* __restrict__ Wg1T, const float* __restrict__ bg1,
    unsigned short* __restrict__ UH, float* __restrict__ Vf)
{
  const int rowL = lane & 15, kq = lane >> 4;
  const int r = wave*16 + rowL;                      // A row (local)
  f32x4 acc[16] = {};
  #pragma unroll
  for(int ks = 0; ks < 4; ks++){
    const int kc = ks*4 + kq;
    bf16x8 a = *(const bf16x8*)&hs[r*128 + ((kc ^ (r & 15)) << 3)];
    #pragma unroll
    for(int nt = 0; nt < 16; nt++){
      bf16x8 b = *(const bf16x8*)(Wg1T + (size_t)(nt*16 + rowL)*128 + ks*32 + kq*8);
      acc[nt] = __builtin_amdgcn_mfma_f32_16x16x32_bf16(a, b, acc[nt], 0, 0, 0);
    }
  }
  #pragma unroll
  for(int nt = 0; nt < 16; nt++){
    const int col = nt*16 + rowL;
    #pragma unroll
    for(int rr = 0; rr < 4; rr++){
      const int gr = row0 + wave*16 + kq*4 + rr;
      if(gr < NN){
        if(col < 128) UH[(size_t)gr*256 + col] = f32_to_bf16(acc[nt][rr]);
        else          Vf[(size_t)gr*128 + col - 128] = acc[nt][rr] + bg1[col - 128];
      }
    }
  }
}

// ---------------- k_uvA: h = relu(h1@W2T + b2); writes UH=[u|h] bf16, Vf=v+bg1 ----------------

__global__ __launch_bounds__(256) void k_uvA(
    const unsigned short* __restrict__ h1, const unsigned short* __restrict__ W2T,
    const float* __restrict__ b2, const unsigned short* __restrict__ Wg1T,
    const float* __restrict__ bg1, unsigned short* __restrict__ UH,
    float* __restrict__ Vf)
{
  __shared__ __attribute__((aligned(16))) unsigned short hs[64*128];
  const int t = threadIdx.x, wave = t >> 6, lane = t & 63;
  const int rowL = lane & 15, kq = lane >> 4;
  const int row0 = blockIdx.x*64;

  // phase 1: h = relu(h1 @ W2T + b2); A direct from global h1, B from L2-resident W2T
  int ar = row0 + wave*16 + rowL; if(ar >= NN) ar = NN-1;
  f32x4 acc[8] = {};
  #pragma unroll
  for(int ks = 0; ks < 4; ks++){
    bf16x8 a = *(const bf16x8*)(h1 + (size_t)ar*128 + ks*32 + kq*8);
    #pragma unroll
    for(int nt = 0; nt < 8; nt++){
      bf16x8 b = *(const bf16x8*)(W2T + (nt*16 + rowL)*128 + ks*32 + kq*8);
      acc[nt] = __builtin_amdgcn_mfma_f32_16x16x32_bf16(a, b, acc[nt], 0, 0, 0);
    }
  }
  // h -> swizzled LDS (bf16 scalars)
  #pragma unroll
  for(int nt = 0; nt < 8; nt++){
    const int col = nt*16 + rowL;
    const float bv = b2[col];
    #pragma unroll
    for(int r = 0; r < 4; r++){
      const int rw = wave*16 + kq*4 + r;
      const unsigned short hv = f32_to_bf16(fmaxf(acc[nt][r] + bv, 0.f));
      hs[rw*128 + (((col >> 3) ^ (rw & 15)) << 3) + (col & 7)] = hv;
    }
  }
  __syncthreads();
  // copy h to UH h-half (coalesced 16B)
  {
    const int r = t >> 2, gr = row0 + r;
    if(gr < NN){
      #pragma unroll
      for(int j8 = 0; j8 < 4; j8++){
        const int chunk = (t & 3)*4 + j8;
        bf16x8 v = *(const bf16x8*)&hs[r*128 + ((chunk ^ (r & 15)) << 3)];
        *(bf16x8*)&UH[(size_t)gr*256 + 128 + chunk*8] = v;
      }
    }
  }
  uv_phase2(hs, row0, wave, lane, Wg1T, bg1, UH, Vf);
}

// ---------------- k_uvB: input h f32 (agg output); writes UH=[u|h] bf16, Vf=v+bg1 ----------------

__global__ __launch_bounds__(256) void k_uvB(
    const float* __restrict__ hf, const unsigned short* __restrict__ Wg1T,
    const float* __restrict__ bg1, unsigned short* __restrict__ UH,
    float* __restrict__ Vf)
{
  __shared__ __attribute__((aligned(16))) unsigned short hs[64*128];
  const int t = threadIdx.x, wave = t >> 6, lane = t & 63;
  const int row0 = blockIdx.x*64;

  {
    const int r = t >> 2, gr0 = row0 + r;
    const int gr = (gr0 < NN) ? gr0 : NN-1;
    const float* p = hf + (size_t)gr*128 + (t & 3)*32;
    #pragma unroll
    for(int j8 = 0; j8 < 4; j8++){
      f32x4 v0 = *(const f32x4*)(p + j8*8);
      f32x4 v1 = *(const f32x4*)(p + j8*8 + 4);
      union { bf16x8 v; unsigned short s[8]; } pk;
      #pragma unroll
      for(int j = 0; j < 4; j++){ pk.s[j] = f32_to_bf16(v0[j]); pk.s[4+j] = f32_to_bf16(v1[j]); }
      const int chunk = (t & 3)*4 + j8;
      *(bf16x8*)&hs[r*128 + ((chunk ^ (r & 15)) << 3)] = pk.v;
      if(gr0 < NN) *(bf16x8*)&UH[(size_t)gr0*256 + 128 + chunk*8] = pk.v;
    }
  }
  __syncthreads();
  uv_phase2(hs, row0, wave, lane & 63, Wg1T, bg1, UH, Vf);
}

// ---------------- fused gate + aggregation, CSR order, one wave per dst node ----------------

__global__ __launch_bounds__(256) void k_gate_agg(
    const unsigned short* __restrict__ UH, const float* __restrict__ Vf,
    const int* __restrict__ row_ptr, const int* __restrict__ src_perm,
    const float* __restrict__ c_perm,
    const float* __restrict__ Wg2, const float* __restrict__ bg2p,
    float* __restrict__ out_f32)
{
  __shared__ float2 ws_s[4][64];
  const int wv = threadIdx.x >> 6, lane = threadIdx.x & 63;
  const int gw = blockIdx.x*4 + wv;
  if(gw >= NN) return;
  const int eq = lane >> 4, li = lane & 15;

  f32x4 va = *(const f32x4*)(Vf + (size_t)gw*128 + li*8);
  f32x4 vb = *(const f32x4*)(Vf + (size_t)gw*128 + li*8 + 4);
  f32x4 wa = *(const f32x4*)(Wg2 + li*8);
  f32x4 wb = *(const f32x4*)(Wg2 + li*8 + 4);
  const float vch[8]  = {va[0],va[1],va[2],va[3],vb[0],vb[1],vb[2],vb[3]};
  const float w2ch[8] = {wa[0],wa[1],wa[2],wa[3],wb[0],wb[1],wb[2],wb[3]};
  const float bg2v = bg2p[0];

  const int beg = row_ptr[gw], end = row_ptr[gw+1];
  float a0 = 0.f, a1 = 0.f, wsum = 0.f;

  for(int base = beg; base < end; base += 64){
    const int nb = min(64, end - base);
    for(int q = 0; q < nb; q += 4){
      const int  idx  = q + eq;
      const bool ok   = (idx < nb);
      const int  slot = base + (ok ? idx : 0);
      const int  s    = src_perm[slot];
      const float cv  = c_perm[slot];
      union { bf16x8 v; uint32_t u32[4]; } uu;
      uu.v = *(const bf16x8*)&UH[(size_t)s*256 + li*8];
      float tacc = 0.f;
      #pragma unroll
      for(int p = 0; p < 4; p++){
        const uint32_t w2b = uu.u32[p];
        tacc += fmaxf(bf16lo_to_f32(w2b) + vch[2*p],   0.f) * w2ch[2*p];
        tacc += fmaxf(bf16hi_to_f32(w2b) + vch[2*p+1], 0.f) * w2ch[2*p+1];
      }
      tacc += __int_as_float(__builtin_amdgcn_ds_swizzle(__float_as_int(tacc), 0x041F));
      tacc += __int_as_float(__builtin_amdgcn_ds_swizzle(__float_as_int(tacc), 0x081F));
      tacc += __int_as_float(__builtin_amdgcn_ds_swizzle(__float_as_int(tacc), 0x101F));
      tacc += __int_as_float(__builtin_amdgcn_ds_swizzle(__float_as_int(tacc), 0x201F));
      const float g = 1.f/(1.f + __expf(-(tacc + bg2v)));
      if(li == 0 && ok) ws_s[wv][idx] = make_float2(cv*g, __int_as_float(s));
    }
    #pragma unroll 4
    for(int j = 0; j < nb; j++){
      const float2 p = ws_s[wv][j];
      const float w  = p.x;
      const int   s  = __float_as_int(p.y);
      const uint32_t hw = *(const uint32_t*)&UH[(size_t)s*256 + 128 + lane*2];
      a0 += w*bf16lo_to_f32(hw);
      a1 += w*bf16hi_to_f32(hw);
      wsum += w;
    }
  }
  const float inv = 1.f/(wsum + EPSV);
  const size_t o = (size_t)gw*128 + lane*2;
  *(f32x2*)&out_f32[o] = (f32x2){a0*inv, a1*inv};
}

// ---------------- launch ----------------

extern "C" void kernel_launch(void* const* d_in, const int* in_sizes, int n_in,
                              void* d_out, int out_size, void* d_ws, size_t ws_size,
                              hipStream_t stream) {
  (void)in_sizes; (void)n_in; (void)out_size; (void)ws_size;
  const float* X      = (const float*)d_in[0];
  const int*   src    = (const int*)d_in[1];
  const int*   dst    = (const int*)d_in[2];
  const float* base_w = (const float*)d_in[3];
  const float* W1     = (const float*)d_in[4];
  const float* b1     = (const float*)d_in[5];
  const float* W2     = (const float*)d_in[6];
  const float* b2     = (const float*)d_in[7];
  const float* Wg1    = (const float*)d_in[8];
  const float* bg1    = (const float*)d_in[9];
  const float* Wg2    = (const float*)d_in[10];
  const float* bg2    = (const float*)d_in[11];
  const float* rho    = (const float*)d_in[12];

  char* ws = (char*)d_ws;
  size_t off = 0;
  auto alloc = [&](size_t bytes)->char*{ char* p = ws + off; off += (bytes + 255) & ~(size_t)255; return p; };
  unsigned short* W1T      = (unsigned short*)alloc((size_t)1024*128*2);
  unsigned short* W2T      = (unsigned short*)alloc((size_t)128*128*2);
  unsigned short* Wg1T     = (unsigned short*)alloc((size_t)256*128*2);
  int*            src_perm = (int*)alloc((size_t)EE*4);
  float*          c_perm   = (float*)alloc((size_t)EE*4);
  int*            row_ptr  = (int*)alloc((size_t)(NN+1)*4);
  int*            cursor   = (int*)alloc((size_t)NN*4);
  int*            counts   = (int*)alloc((size_t)NN*4);
  int*            lexcl    = (int*)alloc((size_t)NN*4);
  int*            bsum     = (int*)alloc((size_t)256*4);
  int*            bexcl    = (int*)alloc((size_t)256*4);
  unsigned short* h1       = (unsigned short*)alloc((size_t)NN*128*2);
  unsigned short* UH       = (unsigned short*)alloc((size_t)NN*256*2);
  float*          Vf       = (float*)alloc((size_t)NN*128*4);
  float*          hf_B     = (float*)alloc((size_t)NN*128*4);

  hipMemsetAsync(counts, 0, (size_t)NN*4, stream);
  k_prep_w1t<<<512, 256, 0, stream>>>(W1, W1T);
  k_prep_w2t<<<64, 256, 0, stream>>>(W2, W2T);
  k_prep_wg1T<<<128, 256, 0, stream>>>(Wg1, Wg1T);
  k_hist<<<EE/256, 256, 0, stream>>>(dst, counts);
  k_scan1<<<SCAN_BLKS, 256, 0, stream>>>(counts, lexcl, bsum);
  k_scan2<<<1, 256, 0, stream>>>(bsum, bexcl, row_ptr);
  k_scan3<<<SCAN_BLKS, 256, 0, stream>>>(lexcl, bexcl, row_ptr, cursor);
  k_fill<<<EE/256, 256, 0, stream>>>(src, dst, base_w, rho, cursor, src_perm, c_perm);

  k_enc1<<<1563, 512, 0, stream>>>(X, W1T, b1, h1);

  // layer 1
  k_uvA<<<782, 256, 0, stream>>>(h1, W2T, b2, Wg1T, bg1, UH, Vf);
  k_gate_agg<<<12500, 256, 0, stream>>>(UH, Vf, row_ptr, src_perm, c_perm, Wg2, bg2, hf_B);
  // layer 2
  k_uvB<<<782, 256, 0, stream>>>(hf_B, Wg1T, bg1, UH, Vf);
  k_gate_agg<<<12500, 256, 0, stream>>>(UH, Vf, row_ptr, src_perm, c_perm, Wg2, bg2, (float*)d_out);
}

// Round 6
// 642.443 us; speedup vs baseline: 1.1251x; 1.1126x over previous
//
#include <hip/hip_runtime.h>
#include <stdint.h>

#define NN 50000
#define CC 1024
#define HH 128
#define EE 1600000
#define EPSV 1e-8f
#define SCAN_BLKS 196   // ceil(50000/256)

typedef __attribute__((ext_vector_type(8))) short bf16x8;
typedef __attribute__((ext_vector_type(4))) float f32x4;
typedef __attribute__((ext_vector_type(2))) float f32x2;

__device__ __forceinline__ unsigned short f32_to_bf16(float f){
  union { float f; uint32_t u; } cv; cv.f = f;
  uint32_t u = cv.u;
  return (unsigned short)((u + 0x7FFFu + ((u >> 16) & 1u)) >> 16);
}
__device__ __forceinline__ float bf16lo_to_f32(uint32_t w){
  union { uint32_t u; float f; } cv; cv.u = w << 16; return cv.f;
}
__device__ __forceinline__ float bf16hi_to_f32(uint32_t w){
  union { uint32_t u; float f; } cv; cv.u = w & 0xFFFF0000u; return cv.f;
}

// ---------------- prep kernels ----------------

__global__ __launch_bounds__(256) void k_prep_w1t(const float* __restrict__ W1,
                                                  unsigned short* __restrict__ W1T){
  int idx = blockIdx.x*256 + threadIdx.x;          // 128*1024, W1T[n][k]
  if(idx >= 128*1024) return;
  int n = idx >> 10, k = idx & 1023;
  W1T[idx] = f32_to_bf16(W1[k*128 + n]);
}

__global__ __launch_bounds__(256) void k_prep_w2t(const float* __restrict__ W2,
                                                  unsigned short* __restrict__ W2T){
  int idx = blockIdx.x*256 + threadIdx.x;          // 128*128, W2T[n][k]
  if(idx >= 128*128) return;
  int n = idx >> 7, k = idx & 127;
  W2T[idx] = f32_to_bf16(W2[k*128 + n]);
}

// Wg1T[c][k], c in [0,256): c<128 -> u-col uses Wg1[k][c]; c>=128 -> v-col uses Wg1[128+k][c-128]
__global__ __launch_bounds__(256) void k_prep_wg1T(const float* __restrict__ Wg1,
                                                   unsigned short* __restrict__ T){
  int idx = blockIdx.x*256 + threadIdx.x;          // 256*128
  if(idx >= 256*128) return;
  int c = idx >> 7, k = idx & 127;
  int row = (c < 128) ? k : (128 + k);
  int col = (c < 128) ? c : (c - 128);
  T[idx] = f32_to_bf16(Wg1[row*128 + col]);
}

// ---------------- CSR build: hist + 3-kernel parallel scan + fill ----------------

__global__ __launch_bounds__(256) void k_hist(const int* __restrict__ dst,
                                              int* __restrict__ counts){
  int e = blockIdx.x*256 + threadIdx.x;
  if(e < EE) atomicAdd(&counts[dst[e]], 1);
}

__global__ __launch_bounds__(256) void k_scan1(const int* __restrict__ counts,
    int* __restrict__ lexcl, int* __restrict__ bsum){
  __shared__ int buf[256];
  const int t = threadIdx.x, i = blockIdx.x*256 + t;
  int v = (i < NN) ? counts[i] : 0;
  buf[t] = v;
  __syncthreads();
  for(int off = 1; off < 256; off <<= 1){
    int add = (t >= off) ? buf[t-off] : 0;
    __syncthreads();
    buf[t] += add;
    __syncthreads();
  }
  if(i < NN) lexcl[i] = buf[t] - v;
  if(t == 255) bsum[blockIdx.x] = buf[255];
}

__global__ __launch_bounds__(256) void k_scan2(const int* __restrict__ bsum,
    int* __restrict__ bexcl, int* __restrict__ row_ptr){
  __shared__ int buf[256];
  const int t = threadIdx.x;
  int v = (t < SCAN_BLKS) ? bsum[t] : 0;
  buf[t] = v;
  __syncthreads();
  for(int off = 1; off < 256; off <<= 1){
    int add = (t >= off) ? buf[t-off] : 0;
    __syncthreads();
    buf[t] += add;
    __syncthreads();
  }
  if(t < SCAN_BLKS) bexcl[t] = buf[t] - v;
  if(t == 255) row_ptr[NN] = buf[255];
}

__global__ __launch_bounds__(256) void k_scan3(const int* __restrict__ lexcl,
    const int* __restrict__ bexcl, int* __restrict__ row_ptr, int* __restrict__ cursor){
  const int i = blockIdx.x*256 + threadIdx.x;
  if(i >= NN) return;
  int e = lexcl[i] + bexcl[blockIdx.x];
  row_ptr[i] = e;
  cursor[i]  = e;
}

// fill CSR slots; computes c = base_w*sig(rho_src)*sig(rho_dst) inline into permuted order
__global__ __launch_bounds__(256) void k_fill(const int* __restrict__ src,
    const int* __restrict__ dst, const float* __restrict__ base_w,
    const float* __restrict__ rho_raw, int* __restrict__ cursor,
    int* __restrict__ src_perm, float* __restrict__ c_perm){
  int e = blockIdx.x*256 + threadIdx.x;
  if(e >= EE) return;
  int s = src[e], d = dst[e];
  int p = atomicAdd(&cursor[d], 1);
  float rs = 1.f/(1.f + __expf(-rho_raw[s]));
  float rd = 1.f/(1.f + __expf(-rho_raw[d]));
  src_perm[p] = s;
  c_perm[p]   = base_w[e]*rs*rd;
}

// ---------------- encoder GEMM1: h1 = relu(X@W1 + b1) -> bf16 [N,128] ----------------
// m97-style double-buffered K-loop. 64x128 tile, BK=32, 4 waves (2M x 2N).
// A (f32->bf16) and B both staged in padded LDS (stride 40 shorts, 30KB dbuf);
// tile k+1 global loads issued before tile k's MFMAs; one barrier per K-step.

__global__ __launch_bounds__(256) void k_enc1(
    const float* __restrict__ X, const unsigned short* __restrict__ W1T,
    const float* __restrict__ b1, unsigned short* __restrict__ h1)
{
  __shared__ __attribute__((aligned(16))) unsigned short As[2][64*40];   //  5120B each
  __shared__ __attribute__((aligned(16))) unsigned short Bs[2][128*40];  // 10240B each

  const int t = threadIdx.x, w = t >> 6, lane = t & 63;
  const int rowL = lane & 15, kq = lane >> 4;
  const int wm = w >> 1, wn = w & 1;
  const int row0 = blockIdx.x * 64;

  // staging ownership: A 4 thr/row (8 f32 each), B 2 thr/row (16 bf16 each)
  const int arow = t >> 2, ac8  = (t & 3) * 8;
  const int brow = t >> 1, bk16 = (t & 1) * 16;
  int ag = row0 + arow; if(ag >= NN) ag = NN - 1;
  const float* xp = X + (size_t)ag*1024 + ac8;
  const unsigned short* wp = W1T + (size_t)brow*1024 + bk16;

  f32x4 ra0 = *(const f32x4*)(xp);
  f32x4 ra1 = *(const f32x4*)(xp + 4);
  bf16x8 rb0 = *(const bf16x8*)(wp);
  bf16x8 rb1 = *(const bf16x8*)(wp + 8);

  { // write tile 0
    union { bf16x8 v; unsigned short s[8]; } pk;
    #pragma unroll
    for(int j = 0; j < 4; j++){ pk.s[j] = f32_to_bf16(ra0[j]); pk.s[4+j] = f32_to_bf16(ra1[j]); }
    *(bf16x8*)&As[0][arow*40 + ac8] = pk.v;
    *(bf16x8*)&Bs[0][brow*40 + bk16]     = rb0;
    *(bf16x8*)&Bs[0][brow*40 + bk16 + 8] = rb1;
  }
  __syncthreads();

  f32x4 acc[2][4] = {};
  int cur = 0;
  for(int k0 = 32; k0 <= 1024; k0 += 32){      // k0 = NEXT tile's K offset
    const bool more = (k0 < 1024);
    if(more){                                   // issue next-tile loads first
      ra0 = *(const f32x4*)(xp + k0);
      ra1 = *(const f32x4*)(xp + k0 + 4);
      rb0 = *(const bf16x8*)(wp + k0);
      rb1 = *(const bf16x8*)(wp + k0 + 8);
    }
    // current-tile fragments + MFMA
    bf16x8 af[2], bfr[4];
    #pragma unroll
    for(int mf = 0; mf < 2; mf++)
      af[mf] = *(const bf16x8*)&As[cur][(wm*32 + mf*16 + rowL)*40 + kq*8];
    #pragma unroll
    for(int nf = 0; nf < 4; nf++)
      bfr[nf] = *(const bf16x8*)&Bs[cur][(wn*64 + nf*16 + rowL)*40 + kq*8];
    #pragma unroll
    for(int mf = 0; mf < 2; mf++)
      #pragma unroll
      for(int nf = 0; nf < 4; nf++)
        acc[mf][nf] = __builtin_amdgcn_mfma_f32_16x16x32_bf16(af[mf], bfr[nf], acc[mf][nf], 0, 0, 0);
    if(more){                                   // convert + stage into other buffer
      union { bf16x8 v; unsigned short s[8]; } pk;
      #pragma unroll
      for(int j = 0; j < 4; j++){ pk.s[j] = f32_to_bf16(ra0[j]); pk.s[4+j] = f32_to_bf16(ra1[j]); }
      *(bf16x8*)&As[cur^1][arow*40 + ac8] = pk.v;
      *(bf16x8*)&Bs[cur^1][brow*40 + bk16]     = rb0;
      *(bf16x8*)&Bs[cur^1][brow*40 + bk16 + 8] = rb1;
    }
    __syncthreads();
    cur ^= 1;
  }

  // epilogue: bias + relu + bf16 store. C frag: row = kq*4+r, col = rowL.
  #pragma unroll
  for(int mf = 0; mf < 2; mf++){
    #pragma unroll
    for(int nf = 0; nf < 4; nf++){
      const int col = wn*64 + nf*16 + rowL;
      const float bv = b1[col];
      #pragma unroll
      for(int r = 0; r < 4; r++){
        const int gr = row0 + wm*32 + mf*16 + kq*4 + r;
        if(gr < NN) h1[(size_t)gr*128 + col] = f32_to_bf16(fmaxf(acc[mf][nf][r] + bv, 0.f));
      }
    }
  }
}

// ---------------- shared UV phase: [u|v] = h @ Wg1T from swizzled LDS h ----------------
// hs: 64 rows x 128 bf16, chunk c of row r stored at chunk (c ^ (r&15)).

__device__ __forceinline__ void uv_phase2(
    const unsigned short* hs, int row0, int wave, int lane,
    const unsigned short* __restrict__ Wg1T, const float* __restrict__ bg1,
    unsigned short* __restrict__ UH, float* __restrict__ Vf)
{
  const int rowL = lane & 15, kq = lane >> 4;
  const int r = wave*16 + rowL;                      // A row (local)
  f32x4 acc[16] = {};
  #pragma unroll
  for(int ks = 0; ks < 4; ks++){
    const int kc = ks*4 + kq;
    bf16x8 a = *(const bf16x8*)&hs[r*128 + ((kc ^ (r & 15)) << 3)];
    #pragma unroll
    for(int nt = 0; nt < 16; nt++){
      bf16x8 b = *(const bf16x8*)(Wg1T + (size_t)(nt*16 + rowL)*128 + ks*32 + kq*8);
      acc[nt] = __builtin_amdgcn_mfma_f32_16x16x32_bf16(a, b, acc[nt], 0, 0, 0);
    }
  }
  #pragma unroll
  for(int nt = 0; nt < 16; nt++){
    const int col = nt*16 + rowL;
    #pragma unroll
    for(int rr = 0; rr < 4; rr++){
      const int gr = row0 + wave*16 + kq*4 + rr;
      if(gr < NN){
        if(col < 128) UH[(size_t)gr*256 + col] = f32_to_bf16(acc[nt][rr]);
        else          Vf[(size_t)gr*128 + col - 128] = acc[nt][rr] + bg1[col - 128];
      }
    }
  }
}

// ---------------- k_uvA: h = relu(h1@W2T + b2); writes UH=[u|h] bf16, Vf=v+bg1 ----------------

__global__ __launch_bounds__(256) void k_uvA(
    const unsigned short* __restrict__ h1, const unsigned short* __restrict__ W2T,
    const float* __restrict__ b2, const unsigned short* __restrict__ Wg1T,
    const float* __restrict__ bg1, unsigned short* __restrict__ UH,
    float* __restrict__ Vf)
{
  __shared__ __attribute__((aligned(16))) unsigned short hs[64*128];
  const int t = threadIdx.x, wave = t >> 6, lane = t & 63;
  const int rowL = lane & 15, kq = lane >> 4;
  const int row0 = blockIdx.x*64;

  // phase 1: h = relu(h1 @ W2T + b2); A direct from global h1, B from L2-resident W2T
  int ar = row0 + wave*16 + rowL; if(ar >= NN) ar = NN-1;
  f32x4 acc[8] = {};
  #pragma unroll
  for(int ks = 0; ks < 4; ks++){
    bf16x8 a = *(const bf16x8*)(h1 + (size_t)ar*128 + ks*32 + kq*8);
    #pragma unroll
    for(int nt = 0; nt < 8; nt++){
      bf16x8 b = *(const bf16x8*)(W2T + (nt*16 + rowL)*128 + ks*32 + kq*8);
      acc[nt] = __builtin_amdgcn_mfma_f32_16x16x32_bf16(a, b, acc[nt], 0, 0, 0);
    }
  }
  // h -> swizzled LDS (bf16 scalars)
  #pragma unroll
  for(int nt = 0; nt < 8; nt++){
    const int col = nt*16 + rowL;
    const float bv = b2[col];
    #pragma unroll
    for(int r = 0; r < 4; r++){
      const int rw = wave*16 + kq*4 + r;
      const unsigned short hv = f32_to_bf16(fmaxf(acc[nt][r] + bv, 0.f));
      hs[rw*128 + (((col >> 3) ^ (rw & 15)) << 3) + (col & 7)] = hv;
    }
  }
  __syncthreads();
  // copy h to UH h-half (coalesced 16B)
  {
    const int r = t >> 2, gr = row0 + r;
    if(gr < NN){
      #pragma unroll
      for(int j8 = 0; j8 < 4; j8++){
        const int chunk = (t & 3)*4 + j8;
        bf16x8 v = *(const bf16x8*)&hs[r*128 + ((chunk ^ (r & 15)) << 3)];
        *(bf16x8*)&UH[(size_t)gr*256 + 128 + chunk*8] = v;
      }
    }
  }
  uv_phase2(hs, row0, wave, lane, Wg1T, bg1, UH, Vf);
}

// ---------------- k_uvB: input h f32 (agg output); writes UH=[u|h] bf16, Vf=v+bg1 ----------------

__global__ __launch_bounds__(256) void k_uvB(
    const float* __restrict__ hf, const unsigned short* __restrict__ Wg1T,
    const float* __restrict__ bg1, unsigned short* __restrict__ UH,
    float* __restrict__ Vf)
{
  __shared__ __attribute__((aligned(16))) unsigned short hs[64*128];
  const int t = threadIdx.x, wave = t >> 6, lane = t & 63;
  const int row0 = blockIdx.x*64;

  {
    const int r = t >> 2, gr0 = row0 + r;
    const int gr = (gr0 < NN) ? gr0 : NN-1;
    const float* p = hf + (size_t)gr*128 + (t & 3)*32;
    #pragma unroll
    for(int j8 = 0; j8 < 4; j8++){
      f32x4 v0 = *(const f32x4*)(p + j8*8);
      f32x4 v1 = *(const f32x4*)(p + j8*8 + 4);
      union { bf16x8 v; unsigned short s[8]; } pk;
      #pragma unroll
      for(int j = 0; j < 4; j++){ pk.s[j] = f32_to_bf16(v0[j]); pk.s[4+j] = f32_to_bf16(v1[j]); }
      const int chunk = (t & 3)*4 + j8;
      *(bf16x8*)&hs[r*128 + ((chunk ^ (r & 15)) << 3)] = pk.v;
      if(gr0 < NN) *(bf16x8*)&UH[(size_t)gr0*256 + 128 + chunk*8] = pk.v;
    }
  }
  __syncthreads();
  uv_phase2(hs, row0, wave, lane & 63, Wg1T, bg1, UH, Vf);
}

// ---------------- fused gate + aggregation, CSR order, one wave per dst node ----------------

__global__ __launch_bounds__(256) void k_gate_agg(
    const unsigned short* __restrict__ UH, const float* __restrict__ Vf,
    const int* __restrict__ row_ptr, const int* __restrict__ src_perm,
    const float* __restrict__ c_perm,
    const float* __restrict__ Wg2, const float* __restrict__ bg2p,
    float* __restrict__ out_f32)
{
  __shared__ float2 ws_s[4][64];
  const int wv = threadIdx.x >> 6, lane = threadIdx.x & 63;
  const int gw = blockIdx.x*4 + wv;
  if(gw >= NN) return;
  const int eq = lane >> 4, li = lane & 15;

  f32x4 va = *(const f32x4*)(Vf + (size_t)gw*128 + li*8);
  f32x4 vb = *(const f32x4*)(Vf + (size_t)gw*128 + li*8 + 4);
  f32x4 wa = *(const f32x4*)(Wg2 + li*8);
  f32x4 wb = *(const f32x4*)(Wg2 + li*8 + 4);
  const float vch[8]  = {va[0],va[1],va[2],va[3],vb[0],vb[1],vb[2],vb[3]};
  const float w2ch[8] = {wa[0],wa[1],wa[2],wa[3],wb[0],wb[1],wb[2],wb[3]};
  const float bg2v = bg2p[0];

  const int beg = row_ptr[gw], end = row_ptr[gw+1];
  float a0 = 0.f, a1 = 0.f, wsum = 0.f;

  for(int base = beg; base < end; base += 64){
    const int nb = min(64, end - base);
    for(int q = 0; q < nb; q += 4){
      const int  idx  = q + eq;
      const bool ok   = (idx < nb);
      const int  slot = base + (ok ? idx : 0);
      const int  s    = src_perm[slot];
      const float cv  = c_perm[slot];
      union { bf16x8 v; uint32_t u32[4]; } uu;
      uu.v = *(const bf16x8*)&UH[(size_t)s*256 + li*8];
      float tacc = 0.f;
      #pragma unroll
      for(int p = 0; p < 4; p++){
        const uint32_t w2b = uu.u32[p];
        tacc += fmaxf(bf16lo_to_f32(w2b) + vch[2*p],   0.f) * w2ch[2*p];
        tacc += fmaxf(bf16hi_to_f32(w2b) + vch[2*p+1], 0.f) * w2ch[2*p+1];
      }
      tacc += __int_as_float(__builtin_amdgcn_ds_swizzle(__float_as_int(tacc), 0x041F));
      tacc += __int_as_float(__builtin_amdgcn_ds_swizzle(__float_as_int(tacc), 0x081F));
      tacc += __int_as_float(__builtin_amdgcn_ds_swizzle(__float_as_int(tacc), 0x101F));
      tacc += __int_as_float(__builtin_amdgcn_ds_swizzle(__float_as_int(tacc), 0x201F));
      const float g = 1.f/(1.f + __expf(-(tacc + bg2v)));
      if(li == 0 && ok) ws_s[wv][idx] = make_float2(cv*g, __int_as_float(s));
    }
    #pragma unroll 4
    for(int j = 0; j < nb; j++){
      const float2 p = ws_s[wv][j];
      const float w  = p.x;
      const int   s  = __float_as_int(p.y);
      const uint32_t hw = *(const uint32_t*)&UH[(size_t)s*256 + 128 + lane*2];
      a0 += w*bf16lo_to_f32(hw);
      a1 += w*bf16hi_to_f32(hw);
      wsum += w;
    }
  }
  const float inv = 1.f/(wsum + EPSV);
  const size_t o = (size_t)gw*128 + lane*2;
  *(f32x2*)&out_f32[o] = (f32x2){a0*inv, a1*inv};
}

// ---------------- launch ----------------

extern "C" void kernel_launch(void* const* d_in, const int* in_sizes, int n_in,
                              void* d_out, int out_size, void* d_ws, size_t ws_size,
                              hipStream_t stream) {
  (void)in_sizes; (void)n_in; (void)out_size; (void)ws_size;
  const float* X      = (const float*)d_in[0];
  const int*   src    = (const int*)d_in[1];
  const int*   dst    = (const int*)d_in[2];
  const float* base_w = (const float*)d_in[3];
  const float* W1     = (const float*)d_in[4];
  const float* b1     = (const float*)d_in[5];
  const float* W2     = (const float*)d_in[6];
  const float* b2     = (const float*)d_in[7];
  const float* Wg1    = (const float*)d_in[8];
  const float* bg1    = (const float*)d_in[9];
  const float* Wg2    = (const float*)d_in[10];
  const float* bg2    = (const float*)d_in[11];
  const float* rho    = (const float*)d_in[12];

  char* ws = (char*)d_ws;
  size_t off = 0;
  auto alloc = [&](size_t bytes)->char*{ char* p = ws + off; off += (bytes + 255) & ~(size_t)255; return p; };
  unsigned short* W1T      = (unsigned short*)alloc((size_t)1024*128*2);
  unsigned short* W2T      = (unsigned short*)alloc((size_t)128*128*2);
  unsigned short* Wg1T     = (unsigned short*)alloc((size_t)256*128*2);
  int*            src_perm = (int*)alloc((size_t)EE*4);
  float*          c_perm   = (float*)alloc((size_t)EE*4);
  int*            row_ptr  = (int*)alloc((size_t)(NN+1)*4);
  int*            cursor   = (int*)alloc((size_t)NN*4);
  int*            counts   = (int*)alloc((size_t)NN*4);
  int*            lexcl    = (int*)alloc((size_t)NN*4);
  int*            bsum     = (int*)alloc((size_t)256*4);
  int*            bexcl    = (int*)alloc((size_t)256*4);
  unsigned short* h1       = (unsigned short*)alloc((size_t)NN*128*2);
  unsigned short* UH       = (unsigned short*)alloc((size_t)NN*256*2);
  float*          Vf       = (float*)alloc((size_t)NN*128*4);
  float*          hf_B     = (float*)alloc((size_t)NN*128*4);

  hipMemsetAsync(counts, 0, (size_t)NN*4, stream);
  k_prep_w1t<<<512, 256, 0, stream>>>(W1, W1T);
  k_prep_w2t<<<64, 256, 0, stream>>>(W2, W2T);
  k_prep_wg1T<<<128, 256, 0, stream>>>(Wg1, Wg1T);
  k_hist<<<EE/256, 256, 0, stream>>>(dst, counts);
  k_scan1<<<SCAN_BLKS, 256, 0, stream>>>(counts, lexcl, bsum);
  k_scan2<<<1, 256, 0, stream>>>(bsum, bexcl, row_ptr);
  k_scan3<<<SCAN_BLKS, 256, 0, stream>>>(lexcl, bexcl, row_ptr, cursor);
  k_fill<<<EE/256, 256, 0, stream>>>(src, dst, base_w, rho, cursor, src_perm, c_perm);

  k_enc1<<<782, 256, 0, stream>>>(X, W1T, b1, h1);

  // layer 1
  k_uvA<<<782, 256, 0, stream>>>(h1, W2T, b2, Wg1T, bg1, UH, Vf);
  k_gate_agg<<<12500, 256, 0, stream>>>(UH, Vf, row_ptr, src_perm, c_perm, Wg2, bg2, hf_B);
  // layer 2
  k_uvB<<<782, 256, 0, stream>>>(hf_B, Wg1T, bg1, UH, Vf);
  k_gate_agg<<<12500, 256, 0, stream>>>(UH, Vf, row_ptr, src_perm, c_perm, Wg2, bg2, (float*)d_out);
}